// Round 3
// baseline (225.758 us; speedup 1.0000x reference)
//
#include <hip/hip_runtime.h>

// Problem constants
#define BATCH 32
#define CIN   256
#define CR    8
#define HDIM  56
#define WDIM  56
#define HW    3136          // 56*56
#define COUT  44            // 8 z_norm + 36 interactions

// Fusion tiling: one block = one image x one band of RB=7 output rows.
#define RB    7             // inner rows per block
#define ZROWS 9             // RB + 1 halo row above + 1 below
#define ZPX   (ZROWS*WDIM)  // 504 z pixels per block (incl. halo)
#define IPX   (RB*WDIM)     // 392 output pixels per block
#define LDSW  512           // padded px dimension of the LDS z tile

// ---------------------------------------------------------------------------
// Fully fused kernel: 1x1 conv reduce (256->8) + BN + ReLU  ->  LDS z tile ->
// depthwise 3x3 * scale + L2 norms + 36 pairwise products -> 44 out channels.
//
// Grid: 256 blocks = 32 images x 8 bands, 512 threads (8 waves).
//   decode b = blk % 32, band = blk / 32  ==>  XCD (= blk % 8 by round-robin)
//   equals b % 8: all 8 bands of an image live on ONE XCD, so the halo rows
//   shared between adjacent bands hit that XCD's L2 instead of re-fetching
//   HBM (recovers the 9/7 halo over-read).
//
// Phase 1: thread t computes z for frame pixel t (t<504) = global row
//   r0-1+t/56, col t%56. Full 256-cin reduce, 2-buffer 16-deep load pipeline
//   (>=16 vmem in flight per wave; 8 waves/CU * 16 * 256B = 32KB in flight
//   > ~22KB needed for peak HBM BW). Rows outside the image store z=0
//   (zero-pad semantics of the dw conv). LDS layout zs[c][px] (channel-
//   planar, stride 512): both the phase-1 store and all phase-2 reads have
//   lane-consecutive px -> conflict-free b32 LDS traffic.
//
// Phase 2: threads 0..391 each produce one output pixel: 9 taps read from
//   LDS (column-OOB taps masked to zero; row-OOB already zero in LDS),
//   * scale, two 8-ch L2 norms, 8 + 36 channel writes (NCHW, coalesced).
// ---------------------------------------------------------------------------
__global__ __launch_bounds__(512) void fused_head(
    const float* __restrict__ x, const float* __restrict__ wr,
    const float* __restrict__ gamma, const float* __restrict__ beta,
    const float* __restrict__ mean, const float* __restrict__ var,
    const float* __restrict__ wdw, const float* __restrict__ scale,
    float* __restrict__ out)
{
    __shared__ float zs[CR][LDSW];     // 16 KB

    const int blk  = blockIdx.x;
    const int b    = blk & 31;         // image  (keeps image's bands on 1 XCD)
    const int band = blk >> 5;         // 0..7
    const int r0   = band * RB;        // first inner row
    const int tid  = threadIdx.x;

    // ---------------- Phase 1: z tile (504 px) ----------------
    {
        const int px  = tid;                    // frame pixel 0..511
        const int lr  = px / WDIM;              // frame row 0..9
        const int col = px - lr * WDIM;
        const int gr  = r0 - 1 + lr;            // global row, -1..62
        const bool rowok = (gr >= 0) && (gr < HDIM);
        const int grc = min(max(gr, 0), HDIM - 1);   // clamped (safe) address
        const float* __restrict__ xp =
            x + (size_t)b * CIN * HW + (size_t)grc * WDIM + col;

        float acc[CR];
#pragma unroll
        for (int c = 0; c < CR; ++c) acc[c] = 0.f;

        float xa[16], xb[16];
        auto loadx = [&](float (&arr)[16], int base) {
#pragma unroll
            for (int j = 0; j < 16; ++j)
                arr[j] = xp[(size_t)(base + j) * HW];   // 256B/wave coalesced
        };
        auto consume = [&](const float (&arr)[16], int base) {
#pragma unroll
            for (int j = 0; j < 16; ++j) {
                const int cin = base + j;               // wave-uniform
#pragma unroll
                for (int c = 0; c < CR; ++c)
                    acc[c] = fmaf(arr[j], wr[c * CIN + cin], acc[c]);
            }
        };

        loadx(xa, 0);
        loadx(xb, 16);
#pragma unroll
        for (int k0 = 0; k0 < CIN; k0 += 32) {
            consume(xa, k0);
            if (k0 + 32 < CIN) loadx(xa, k0 + 32);   // in flight over xb-consume
            consume(xb, k0 + 16);
            if (k0 + 48 < CIN) loadx(xb, k0 + 48);   // in flight over xa-consume
        }

        if (px < ZPX) {
#pragma unroll
            for (int c = 0; c < CR; ++c) {
                const float inv = gamma[c] / sqrtf(var[c] + 1e-5f);
                const float sh  = beta[c] - mean[c] * inv;
                const float v   = fmaxf(fmaf(acc[c], inv, sh), 0.f);
                zs[c][px] = rowok ? v : 0.f;        // zero-pad rows
            }
        }
    }
    __syncthreads();

    // ---------------- Phase 2: dw conv + norms + interactions ----------------
    if (tid < IPX) {
        const int p   = tid;                    // inner pixel 0..391
        const int f   = p + WDIM;               // frame index (skip halo row)
        const int lr  = p / WDIM;
        const int col = p - lr * WDIM;

        float zc[CR];
#pragma unroll
        for (int c = 0; c < CR; ++c) zc[c] = zs[c][f];

        float tw[CR];
#pragma unroll
        for (int c = 0; c < CR; ++c) tw[c] = 0.f;

#pragma unroll
        for (int dy = -1; dy <= 1; ++dy) {
#pragma unroll
            for (int dx = -1; dx <= 1; ++dx) {
                const int k = (dy + 1) * 3 + (dx + 1);
                // column mask (row-OOB taps are already 0 in LDS)
                const float m = (dx == 0) ? 1.f
                              : (dx < 0 ? (col > 0  ? 1.f : 0.f)
                                        : (col < WDIM - 1 ? 1.f : 0.f));
                const int idx = max(f + dy * WDIM + dx, 0);   // only p=0,dy=dx=-1 hits -1
#pragma unroll
                for (int c = 0; c < CR; ++c)
                    tw[c] = fmaf(zs[c][idx] * m, wdw[c * 9 + k], tw[c]);
            }
        }

        float s1 = 0.f, s2 = 0.f;
#pragma unroll
        for (int c = 0; c < CR; ++c) {
            tw[c] *= scale[c];
            s1 = fmaf(zc[c], zc[c], s1);
            s2 = fmaf(tw[c], tw[c], s2);
        }
        const float r1 = 1.0f / fmaxf(sqrtf(s1), 1e-6f);
        const float r2 = 1.0f / fmaxf(sqrtf(s2), 1e-6f);

        float a[CR], tb[CR];
#pragma unroll
        for (int c = 0; c < CR; ++c) { a[c] = zc[c] * r1; tb[c] = tw[c] * r2; }

        // 44 output channels (NCHW); lanes have consecutive p -> coalesced
        float* op = out + (size_t)b * COUT * HW + (size_t)r0 * WDIM + p;
#pragma unroll
        for (int c = 0; c < CR; ++c)
            op[(size_t)c * HW] = a[c];

        int idx = CR;
#pragma unroll
        for (int i = 0; i < CR; ++i) {
#pragma unroll
            for (int j = i; j < CR; ++j) {
                op[(size_t)idx * HW] = a[i] * tb[j];
                ++idx;
            }
        }
    }
}

extern "C" void kernel_launch(void* const* d_in, const int* in_sizes, int n_in,
                              void* d_out, int out_size, void* d_ws, size_t ws_size,
                              hipStream_t stream) {
    const float* x     = (const float*)d_in[0];
    const float* wr    = (const float*)d_in[1];
    const float* gamma = (const float*)d_in[2];
    const float* beta  = (const float*)d_in[3];
    const float* mean  = (const float*)d_in[4];
    const float* var   = (const float*)d_in[5];
    const float* wdw   = (const float*)d_in[6];
    const float* scale = (const float*)d_in[7];
    float* out = (float*)d_out;
    (void)d_ws; (void)ws_size;   // z lives in LDS now

    // 256 blocks = 32 images * 8 bands; decode keeps an image's bands on 1 XCD
    fused_head<<<BATCH * 8, 512, 0, stream>>>(x, wr, gamma, beta, mean, var,
                                              wdw, scale, out);
}

// Round 4
// 172.618 us; speedup vs baseline: 1.3078x; 1.3078x over previous
//
#include <hip/hip_runtime.h>

// Problem constants
#define BATCH 32
#define CIN   256
#define CR    8
#define HDIM  56
#define WDIM  56
#define HW    3136          // 56*56 = 49*64 (waves never straddle batch rows)
#define COUT  44            // 8 z_norm + 36 interactions

// ---------------------------------------------------------------------------
// Kernel 1: 1x1 conv reduce (256 -> 8) + BatchNorm(inference) + ReLU.
// 512-thread block = 8 waves sharing 64 pixels; wave w reduces cin
// [32w, 32w+32) in 4 software-pipelined batches of 8 loads (L0 L1 C0 L2 C1
// L3 C2 C3 -> 8..16 loads always in flight per wave). Grid 1568 blocks x 8
// waves = 12544 waves; __launch_bounds__(512,8) keeps VGPR <= 64 so up to
// 4 blocks/CU = 32 waves/CU resident -> 64-128 KB in flight per CU, ~4x the
// ~23 KB needed to saturate HBM. Per-wave weight footprint is only 256
// scalar loads (vs 2048 in the 4-way split). 16 KB LDS combines the 8
// cin-group partials; BN+ReLU fused on the way out.
// z written channels-last [pixel][8] (32B/pixel) for kernel 2.
// ---------------------------------------------------------------------------
__global__ __launch_bounds__(512, 8) void k1_reduce_bn_relu(
    const float* __restrict__ x, const float* __restrict__ wr,
    const float* __restrict__ gamma, const float* __restrict__ beta,
    const float* __restrict__ mean, const float* __restrict__ var,
    float* __restrict__ z)
{
    const int tid  = threadIdx.x;
    const int lane = tid & 63;
    // readfirstlane: provably wave-uniform -> weight addresses stay scalar
    const int wv   = __builtin_amdgcn_readfirstlane(tid >> 6);   // 0..7
    const int pix0 = blockIdx.x * 64;            // block's 64 pixels
    const int gp   = pix0 + lane;
    const int b    = gp / HW;
    const int p    = gp - b * HW;
    const int cin0 = wv * 32;                    // this wave's cin group

    const float* __restrict__ xq =
        x + (size_t)b * CIN * HW + (size_t)cin0 * HW + p;

    float acc[CR];
#pragma unroll
    for (int c = 0; c < CR; ++c) acc[c] = 0.f;

    float xa[8], xb[8];
    auto loadx = [&](float (&arr)[8], int base) {
#pragma unroll
        for (int j = 0; j < 8; ++j)
            arr[j] = xq[(size_t)(base + j) * HW];   // 256B/wave coalesced
    };
    auto consume = [&](const float (&arr)[8], int base) {
#pragma unroll
        for (int j = 0; j < 8; ++j) {
            const int cin = cin0 + base + j;        // wave-uniform
#pragma unroll
            for (int c = 0; c < CR; ++c)
                acc[c] = fmaf(arr[j], wr[c * CIN + cin], acc[c]);
        }
    };

    loadx(xa, 0);
    loadx(xb, 8);            // 16 loads in flight
    consume(xa, 0);
    loadx(xa, 16);           // issued while xb still in flight
    consume(xb, 8);
    loadx(xb, 24);
    consume(xa, 16);
    consume(xb, 24);

    // cross-wave reduction of the 8 cin-group partials
    __shared__ float pacc[8][64][CR];            // 16 KB
#pragma unroll
    for (int c = 0; c < CR; c += 4)
        *reinterpret_cast<float4*>(&pacc[wv][lane][c]) =
            make_float4(acc[c], acc[c + 1], acc[c + 2], acc[c + 3]);
    __syncthreads();

    // 512 outputs (64 px * 8 ch), 512 threads -> 1 each; e = px*8 + c, so the
    // LDS reads are consecutive-address (conflict-free) and the final store
    // z[pix0*8 + tid] is fully coalesced (1KB/wave).
    const int c  = tid & 7;
    const int px = tid >> 3;
    float s = 0.f;
#pragma unroll
    for (int w = 0; w < 8; ++w) s += pacc[w][px][c];
    const float inv = gamma[c] / sqrtf(var[c] + 1e-5f);
    const float sh  = beta[c] - mean[c] * inv;
    z[(size_t)pix0 * CR + tid] = fmaxf(fmaf(s, inv, sh), 0.f);
}

// ---------------------------------------------------------------------------
// Kernel 2 (UNCHANGED from R2 — baseline term for the timing subtraction):
// depthwise 3x3 (pad 1) * scale, per-pixel L2 norms over 8 channels,
// 36 upper-triangular pairwise products, write 44 output channels (NCHW).
// All 9 taps (18 float4 loads) issued into registers before any FMA.
// ---------------------------------------------------------------------------
__global__ __launch_bounds__(64) void k2_dw_norm_inter(
    const float* __restrict__ z, const float* __restrict__ wdw,
    const float* __restrict__ scale, float* __restrict__ out)
{
    const int t = blockIdx.x * 64 + threadIdx.x;   // global pixel id
    const int b = t / HW;
    const int p = t - b * HW;
    const int h = p / WDIM;
    const int w = p - h * WDIM;
    const float* __restrict__ zimg = z + (size_t)b * HW * CR;

    // ---- issue all 9 tap loads first (fully unrolled -> static reg indices)
    float4 n0[9], n1[9];
    float  mk[9];
#pragma unroll
    for (int dy = -1; dy <= 1; ++dy) {
#pragma unroll
        for (int dx = -1; dx <= 1; ++dx) {
            const int k  = (dy + 1) * 3 + (dx + 1);
            const int hh = h + dy, ww = w + dx;
            const bool ok = (hh >= 0) & (hh < HDIM) & (ww >= 0) & (ww < WDIM);
            const int hc = min(max(hh, 0), HDIM - 1);
            const int wc = min(max(ww, 0), WDIM - 1);
            mk[k] = ok ? 1.0f : 0.0f;            // per-lane mask (tap4 -> 1)
            const float* zn = zimg + (size_t)(hc * WDIM + wc) * CR;
            n0[k] = reinterpret_cast<const float4*>(zn)[0];
            n1[k] = reinterpret_cast<const float4*>(zn)[1];
        }
    }

    // center channels = tap 4 (always in-bounds)
    const float zc[CR] = {n0[4].x, n0[4].y, n0[4].z, n0[4].w,
                          n1[4].x, n1[4].y, n1[4].z, n1[4].w};

    // ---- depthwise 3x3
    float tw[CR];
#pragma unroll
    for (int c = 0; c < CR; ++c) tw[c] = 0.f;
#pragma unroll
    for (int k = 0; k < 9; ++k) {
        const float nv[CR] = {n0[k].x, n0[k].y, n0[k].z, n0[k].w,
                              n1[k].x, n1[k].y, n1[k].z, n1[k].w};
#pragma unroll
        for (int c = 0; c < CR; ++c)
            tw[c] = fmaf(nv[c] * mk[k], wdw[c * 9 + k], tw[c]);
    }

    // ---- norms
    float s1 = 0.f, s2 = 0.f;
#pragma unroll
    for (int c = 0; c < CR; ++c) {
        tw[c] *= scale[c];
        s1 = fmaf(zc[c], zc[c], s1);
        s2 = fmaf(tw[c], tw[c], s2);
    }
    const float r1 = 1.0f / fmaxf(sqrtf(s1), 1e-6f);
    const float r2 = 1.0f / fmaxf(sqrtf(s2), 1e-6f);

    float a[CR], tb[CR];
#pragma unroll
    for (int c = 0; c < CR; ++c) { a[c] = zc[c] * r1; tb[c] = tw[c] * r2; }

    // ---- 44 output channels (NCHW), 256B/wave coalesced per channel
    float* op = out + (size_t)b * COUT * HW + p;
#pragma unroll
    for (int c = 0; c < CR; ++c)
        op[(size_t)c * HW] = a[c];

    int idx = CR;
#pragma unroll
    for (int i = 0; i < CR; ++i) {
#pragma unroll
        for (int j = i; j < CR; ++j) {
            op[(size_t)idx * HW] = a[i] * tb[j];
            ++idx;
        }
    }
}

extern "C" void kernel_launch(void* const* d_in, const int* in_sizes, int n_in,
                              void* d_out, int out_size, void* d_ws, size_t ws_size,
                              hipStream_t stream) {
    const float* x     = (const float*)d_in[0];
    const float* wr    = (const float*)d_in[1];
    const float* gamma = (const float*)d_in[2];
    const float* beta  = (const float*)d_in[3];
    const float* mean  = (const float*)d_in[4];
    const float* var   = (const float*)d_in[5];
    const float* wdw   = (const float*)d_in[6];
    const float* scale = (const float*)d_in[7];
    float* out = (float*)d_out;
    float* z   = (float*)d_ws;   // BATCH*HW*CR floats = 3.21 MB, channels-last

    const int npix = BATCH * HW;              // 100352
    k1_reduce_bn_relu<<<npix / 64, 512, 0, stream>>>(x, wr, gamma, beta, mean, var, z);
    k2_dw_norm_inter<<<npix / 64, 64, 0, stream>>>(z, wdw, scale, out);
}